// Round 13
// baseline (187.069 us; speedup 1.0000x reference)
//
#include <hip/hip_runtime.h>
#include <hip/hip_fp16.h>
#include <cstdint>
#include <cstddef>

#define B_ 512
#define T_ 256
#define N_ 128
#define H_ 64
#define G_ 256  // 4H

typedef __attribute__((ext_vector_type(8))) short short8;
typedef __attribute__((ext_vector_type(4))) float f32x4;
typedef _Float16 half2_t __attribute__((ext_vector_type(2)));

static __device__ __forceinline__ unsigned short f2bf(float f) {
    union { float f; unsigned int i; } v;
    v.f = f;
    unsigned int x = v.i;
    return (unsigned short)((x + 0x7fffu + ((x >> 16) & 1u)) >> 16);  // RNE
}
static __device__ __forceinline__ half2_t u2h2(unsigned int u) {
    union { unsigned int u; half2_t h; } v; v.u = u; return v.h;
}

// ---------------------------------------------------------------------------
// K0: pack W_hh (f32 [4H][H]) -> wpack uint4 [4][8][64]: wpack[g][q][j] =
// half2x4 of W_hh[g*64+j][8q..8q+7].  Exactly the per-lane order k_rnn11 loads.
// ---------------------------------------------------------------------------
__global__ __launch_bounds__(256) void k_wpack(const float* __restrict__ W_hh,
                                               uint4* __restrict__ wpack) {
    int idx = blockIdx.x * 256 + threadIdx.x;   // 2048 entries
    if (idx >= 2048) return;
    int g = idx >> 9, q = (idx >> 6) & 7, j = idx & 63;
    const float* src = W_hh + ((size_t)(g * H_ + j)) * H_ + q * 8;
    float4 a = *(const float4*)(src);
    float4 b = *(const float4*)(src + 4);
    union { uint4 u; half2_t h[4]; } pk;
    pk.h[0] = (half2_t){(_Float16)a.x, (_Float16)a.y};
    pk.h[1] = (half2_t){(_Float16)a.z, (_Float16)a.w};
    pk.h[2] = (half2_t){(_Float16)b.x, (_Float16)b.y};
    pk.h[3] = (half2_t){(_Float16)b.z, (_Float16)b.w};
    wpack[idx] = pk.u;
}

// ---------------------------------------------------------------------------
// K1+K2 fused (unchanged: ~48us, BW floor ~37us — later target).
// ---------------------------------------------------------------------------
__global__ __launch_bounds__(256) void k_awgemm(const float* __restrict__ x,
                                                const float* __restrict__ attn_w,
                                                const float* __restrict__ W_ih,
                                                const float* __restrict__ b_ih,
                                                const float* __restrict__ b_hh,
                                                float* __restrict__ iw,
                                                _Float16* __restrict__ gatesx) {
    __shared__ __align__(16) unsigned short Wl[G_][136];  // bf16 W_ih, padded
    __shared__ __align__(16) unsigned short Al[32][136];  // bf16 wx tile (overlaid: red)
    __shared__ float bias[G_];
    __shared__ float aw_s[T_];
    __shared__ float a_s[N_];
    __shared__ float wred[4];
    const int tid = threadIdx.x;
    const int b = blockIdx.x;

    for (int q = tid; q < G_ * 32; q += 256) {
        int r = q >> 5, c4 = (q & 31) << 2;
        float4 v = *(const float4*)(W_ih + r * N_ + c4);
        Wl[r][c4 + 0] = f2bf(v.x); Wl[r][c4 + 1] = f2bf(v.y);
        Wl[r][c4 + 2] = f2bf(v.z); Wl[r][c4 + 3] = f2bf(v.w);
    }
    bias[tid] = b_ih[tid] + b_hh[tid];
    aw_s[tid] = attn_w[2 * H_ + tid];
    __syncthreads();

    // ---- Phase A: attention softmax (shift-invariance kills h/c/bias) ----
    float (*red)[128] = (float(*)[128])&Al[0][0];
    const int n0 = (tid & 31) << 2;
    const int tg = tid >> 5;
    const float* xb = x + (size_t)b * (T_ * N_);
    {
        float p0 = 0.f, p1 = 0.f, p2 = 0.f, p3 = 0.f;
        for (int t = tg; t < T_; t += 8) {
            float4 v = *(const float4*)(xb + t * N_ + n0);
            float w = aw_s[t];
            p0 += v.x * w; p1 += v.y * w; p2 += v.z * w; p3 += v.w * w;
        }
        red[tg][n0 + 0] = p0; red[tg][n0 + 1] = p1;
        red[tg][n0 + 2] = p2; red[tg][n0 + 3] = p3;
    }
    __syncthreads();
    {
        float s = 0.f;
        if (tid < 128) {
            #pragma unroll
            for (int g = 0; g < 8; ++g) s += red[g][tid];
        }
        float m = (tid < 128) ? s : -1e30f;
        #pragma unroll
        for (int d = 1; d < 64; d <<= 1) m = fmaxf(m, __shfl_xor(m, d));
        if ((tid & 63) == 0) wred[tid >> 6] = m;
        __syncthreads();
        m = fmaxf(wred[0], wred[1]);
        __syncthreads();
        float e = (tid < 128) ? __expf(s - m) : 0.f;
        float z = e;
        #pragma unroll
        for (int d = 1; d < 64; d <<= 1) z += __shfl_xor(z, d);
        if ((tid & 63) == 0) wred[tid >> 6] = z;
        __syncthreads();
        z = wred[0] + wred[1];
        if (tid < 128) a_s[tid] = e / z;
    }
    __syncthreads();

    // ---- Phase B: weighting + MFMA GEMM ----
    const int lane = tid & 63;
    const int lr = lane & 15;
    const int lk = (lane >> 4) << 3;
    const int gc0 = (tid >> 6) << 6;
    const int orow = (lane >> 4) << 2;

    for (int st = 0; st < 8; ++st) {
        const int r0 = b * T_ + st * 32;
        __syncthreads();
        for (int q = tid; q < 32 * 32; q += 256) {
            int r = q >> 5, c4 = (q & 31) << 2;
            size_t off = (size_t)(r0 + r) * N_ + c4;
            float4 v = *(const float4*)(x + off);
            float4 w;
            w.x = a_s[c4 + 0] * v.x; w.y = a_s[c4 + 1] * v.y;
            w.z = a_s[c4 + 2] * v.z; w.w = a_s[c4 + 3] * v.w;
            *(float4*)(iw + off) = w;            // output 0 (f32, exact)
            Al[r][c4 + 0] = f2bf(w.x); Al[r][c4 + 1] = f2bf(w.y);
            Al[r][c4 + 2] = f2bf(w.z); Al[r][c4 + 3] = f2bf(w.w);
        }
        __syncthreads();

        f32x4 acc[2][4];
        #pragma unroll
        for (int mt = 0; mt < 2; ++mt)
            #pragma unroll
            for (int nt = 0; nt < 4; ++nt)
                acc[mt][nt] = (f32x4){0.f, 0.f, 0.f, 0.f};

        #pragma unroll
        for (int kk = 0; kk < N_; kk += 32) {
            short8 af0 = *(const short8*)(&Al[lr][kk + lk]);
            short8 af1 = *(const short8*)(&Al[16 + lr][kk + lk]);
            #pragma unroll
            for (int nt = 0; nt < 4; ++nt) {
                short8 bfv = *(const short8*)(&Wl[gc0 + nt * 16 + lr][kk + lk]);
                acc[0][nt] = __builtin_amdgcn_mfma_f32_16x16x32_bf16(af0, bfv, acc[0][nt], 0, 0, 0);
                acc[1][nt] = __builtin_amdgcn_mfma_f32_16x16x32_bf16(af1, bfv, acc[1][nt], 0, 0, 0);
            }
        }
        // D: col = gc0+nt*16+lr (gate index), row = mt*16+(lane>>4)*4+reg
        #pragma unroll
        for (int mt = 0; mt < 2; ++mt) {
            #pragma unroll
            for (int nt = 0; nt < 4; ++nt) {
                int col = gc0 + nt * 16 + lr;
                float bs = bias[col];
                int cell = col & 63, qg = col >> 6;
                #pragma unroll
                for (int rg = 0; rg < 4; ++rg) {
                    int rr = r0 + mt * 16 + orow + rg;
                    gatesx[((size_t)rr * H_ + cell) * 4 + qg] =
                        (_Float16)(acc[mt][nt][rg] + bs);
                }
            }
        }
    }
}

// ---------------------------------------------------------------------------
// K3: LSTM recurrence, single-wave blocks (64 thr), 512 blocks.
// Round-12 finding: readlane vs LDS broadcast identical (134 vs 133us) ->
// issue accounting says ~900cy/step is MEMORY LATENCY EXPOSURE. Theory: the
// compiler (reg-targeting 132 VGPR) interleaves each ds_read_b128 with its
// consumer group -> 8 serialized ~120cy LDS latencies per step (~720cy).
// Fix: ONE asm block issuing all 8 ds_read_b128 (8 forced-live uint4 outputs)
// + single lgkmcnt(0) + sched_barrier(0) (rule #18), then pure-reg fdot2s.
// Reads pipeline: ~150cy total instead of ~960.
// ---------------------------------------------------------------------------
__global__ __attribute__((amdgpu_flat_work_group_size(64, 64)))
__attribute__((amdgpu_waves_per_eu(1, 1)))
void k_rnn11(const _Float16* __restrict__ gatesx,
             const uint4* __restrict__ wpack,
             float* __restrict__ enc) {
    __shared__ __align__(16) _Float16 hs[H_];   // h_t (f16), 128 B
    const int j = threadIdx.x;   // cell index
    const int b = blockIdx.x;

    // 32 x dwordx4 = 128 VGPRs of packed half2 weights (4 gate rows x 8 quads)
    uint4 wv[4][8];
    #pragma unroll
    for (int g = 0; g < 4; ++g) {
        #pragma unroll
        for (int q = 0; q < 8; ++q) {
            unsigned voff = (unsigned)((((g << 3) + q) * 64 + j) << 4);
            asm volatile("global_load_dwordx4 %0, %1, %2"
                         : "=v"(wv[g][q]) : "v"(voff), "s"(wpack) : "memory");
        }
    }
    asm volatile("s_waitcnt vmcnt(0)" ::: "memory");

    hs[j] = (_Float16)0.f;     // h_{-1} = 0 (single wave: DS in-order)
    float c = 0.f;
    const unsigned hbase = (unsigned)(uintptr_t)&hs[0];   // LDS byte offset

    const _Float16* gx = gatesx + ((size_t)b * T_ * H_ + j) * 4;
    float* ep = enc + (size_t)b * T_ * H_ + j;

    uint2 gA = *(const uint2*)(gx);            // t = 0
    uint2 gB = *(const uint2*)(gx + G_);       // t = 1

#define DOTQ(Q, CH)                                                         \
        do {                                                                \
            a0 = __builtin_amdgcn_fdot2(u2h2(wv[0][Q].x), u2h2(CH.x), a0, false); \
            a1 = __builtin_amdgcn_fdot2(u2h2(wv[1][Q].x), u2h2(CH.x), a1, false); \
            a2 = __builtin_amdgcn_fdot2(u2h2(wv[2][Q].x), u2h2(CH.x), a2, false); \
            a3 = __builtin_amdgcn_fdot2(u2h2(wv[3][Q].x), u2h2(CH.x), a3, false); \
            a0 = __builtin_amdgcn_fdot2(u2h2(wv[0][Q].y), u2h2(CH.y), a0, false); \
            a1 = __builtin_amdgcn_fdot2(u2h2(wv[1][Q].y), u2h2(CH.y), a1, false); \
            a2 = __builtin_amdgcn_fdot2(u2h2(wv[2][Q].y), u2h2(CH.y), a2, false); \
            a3 = __builtin_amdgcn_fdot2(u2h2(wv[3][Q].y), u2h2(CH.y), a3, false); \
            a0 = __builtin_amdgcn_fdot2(u2h2(wv[0][Q].z), u2h2(CH.z), a0, false); \
            a1 = __builtin_amdgcn_fdot2(u2h2(wv[1][Q].z), u2h2(CH.z), a1, false); \
            a2 = __builtin_amdgcn_fdot2(u2h2(wv[2][Q].z), u2h2(CH.z), a2, false); \
            a3 = __builtin_amdgcn_fdot2(u2h2(wv[3][Q].z), u2h2(CH.z), a3, false); \
            a0 = __builtin_amdgcn_fdot2(u2h2(wv[0][Q].w), u2h2(CH.w), a0, false); \
            a1 = __builtin_amdgcn_fdot2(u2h2(wv[1][Q].w), u2h2(CH.w), a1, false); \
            a2 = __builtin_amdgcn_fdot2(u2h2(wv[2][Q].w), u2h2(CH.w), a2, false); \
            a3 = __builtin_amdgcn_fdot2(u2h2(wv[3][Q].w), u2h2(CH.w), a3, false); \
        } while (0)

#define STEP(GREG, TNEXT)                                                   \
    {                                                                       \
        half2_t gif = u2h2(GREG.x), ggo = u2h2(GREG.y);                     \
        float a0 = (float)gif.x, a1 = (float)gif.y;                         \
        float a2 = (float)ggo.x, a3 = (float)ggo.y;                         \
        int tn_ = (TNEXT) < T_ ? (TNEXT) : (T_ - 1);                        \
        GREG = *(const uint2*)(gx + (size_t)tn_ * G_);                      \
        uint4 c0, c1, c2, c3, c4, c5, c6, c7;                               \
        asm volatile(                                                       \
            "ds_read_b128 %0, %8 offset:0\n\t"                              \
            "ds_read_b128 %1, %8 offset:16\n\t"                             \
            "ds_read_b128 %2, %8 offset:32\n\t"                             \
            "ds_read_b128 %3, %8 offset:48\n\t"                             \
            "ds_read_b128 %4, %8 offset:64\n\t"                             \
            "ds_read_b128 %5, %8 offset:80\n\t"                             \
            "ds_read_b128 %6, %8 offset:96\n\t"                             \
            "ds_read_b128 %7, %8 offset:112"                                \
            : "=&v"(c0), "=&v"(c1), "=&v"(c2), "=&v"(c3),                   \
              "=&v"(c4), "=&v"(c5), "=&v"(c6), "=&v"(c7)                    \
            : "v"(hbase)                                                    \
            : "memory");                                                    \
        asm volatile("s_waitcnt lgkmcnt(0)" ::: "memory");                  \
        __builtin_amdgcn_sched_barrier(0);                                  \
        DOTQ(0, c0); DOTQ(1, c1); DOTQ(2, c2); DOTQ(3, c3);                 \
        DOTQ(4, c4); DOTQ(5, c5); DOTQ(6, c6); DOTQ(7, c7);                 \
        float si = 1.f / (1.f + __expf(-a0));                               \
        float sf = 1.f / (1.f + __expf(-a1));                               \
        float tg = 1.f - 2.f / (__expf(2.f * a2) + 1.f);                    \
        float so = 1.f / (1.f + __expf(-a3));                               \
        c = sf * c + si * tg;                                               \
        float tc = 1.f - 2.f / (__expf(2.f * c) + 1.f);                     \
        float h = so * tc;                                                  \
        hs[j] = (_Float16)h;      /* in-order DS: visible to next step */   \
        *ep = h;                                                            \
        ep += H_;                                                           \
    }

    for (int t = 0; t < T_; t += 2) {
        STEP(gA, t + 2);
        STEP(gB, t + 3);
    }
#undef STEP
#undef DOTQ
}

extern "C" void kernel_launch(void* const* d_in, const int* in_sizes, int n_in,
                              void* d_out, int out_size, void* d_ws, size_t ws_size,
                              hipStream_t stream) {
    if (n_in < 7 || in_sizes[0] != B_ * T_ * N_) return;

    const float* x    = (const float*)d_in[0];
    const float* aw   = (const float*)d_in[1];
    // d_in[2] (attn_b) provably cancels in the softmax — unused.
    const float* W_ih = (const float*)d_in[3];
    const float* W_hh = (const float*)d_in[4];
    const float* b_ih = (const float*)d_in[5];
    const float* b_hh = (const float*)d_in[6];

    float* iwp = (float*)d_out;                          // (B,T,N) f32
    float* enc = (float*)d_out + (size_t)B_ * T_ * N_;   // (B,T,H) f32

    size_t gx_bytes = (size_t)B_ * T_ * G_ * sizeof(_Float16);   // 33.5 MB
    _Float16* gatesx = (_Float16*)d_ws;
    uint4* wpack = (uint4*)((char*)d_ws + gx_bytes);             // 32 KB
    size_t need = gx_bytes + 2048 * sizeof(uint4);
    if (ws_size < need) return;  // fail loudly rather than corrupt

    hipLaunchKernelGGL(k_wpack, dim3(8), dim3(256), 0, stream, W_hh, wpack);
    hipLaunchKernelGGL(k_awgemm, dim3(B_), dim3(256), 0, stream,
                       x, aw, W_ih, b_ih, b_hh, iwp, gatesx);
    hipLaunchKernelGGL(k_rnn11, dim3(B_), dim3(64), 0, stream, gatesx, wpack, enc);
}

// Round 14
// 185.110 us; speedup vs baseline: 1.0106x; 1.0106x over previous
//
#include <hip/hip_runtime.h>
#include <hip/hip_fp16.h>
#include <cstdint>
#include <cstddef>

#define B_ 512
#define T_ 256
#define N_ 128
#define H_ 64
#define G_ 256  // 4H

typedef __attribute__((ext_vector_type(8))) short short8;
typedef __attribute__((ext_vector_type(4))) float f32x4;
typedef _Float16 half2_t __attribute__((ext_vector_type(2)));

static __device__ __forceinline__ unsigned short f2bf(float f) {
    union { float f; unsigned int i; } v;
    v.f = f;
    unsigned int x = v.i;
    return (unsigned short)((x + 0x7fffu + ((x >> 16) & 1u)) >> 16);  // RNE
}
static __device__ __forceinline__ half2_t u2h2(unsigned int u) {
    union { unsigned int u; half2_t h; } v; v.u = u; return v.h;
}

// ---------------------------------------------------------------------------
// K0: pack W_hh (f32 [4H][H]) -> wpack uint4 [4][8][64]: wpack[g][q][j] =
// half2x4 of W_hh[g*64+j][8q..8q+7].  Exactly the per-lane order k_rnn12 loads.
// ---------------------------------------------------------------------------
__global__ __launch_bounds__(256) void k_wpack(const float* __restrict__ W_hh,
                                               uint4* __restrict__ wpack) {
    int idx = blockIdx.x * 256 + threadIdx.x;   // 2048 entries
    if (idx >= 2048) return;
    int g = idx >> 9, q = (idx >> 6) & 7, j = idx & 63;
    const float* src = W_hh + ((size_t)(g * H_ + j)) * H_ + q * 8;
    float4 a = *(const float4*)(src);
    float4 b = *(const float4*)(src + 4);
    union { uint4 u; half2_t h[4]; } pk;
    pk.h[0] = (half2_t){(_Float16)a.x, (_Float16)a.y};
    pk.h[1] = (half2_t){(_Float16)a.z, (_Float16)a.w};
    pk.h[2] = (half2_t){(_Float16)b.x, (_Float16)b.y};
    pk.h[3] = (half2_t){(_Float16)b.z, (_Float16)b.w};
    wpack[idx] = pk.u;
}

// ---------------------------------------------------------------------------
// K1+K2 fused (unchanged: ~48us, BW floor ~37us).
// ---------------------------------------------------------------------------
__global__ __launch_bounds__(256) void k_awgemm(const float* __restrict__ x,
                                                const float* __restrict__ attn_w,
                                                const float* __restrict__ W_ih,
                                                const float* __restrict__ b_ih,
                                                const float* __restrict__ b_hh,
                                                float* __restrict__ iw,
                                                _Float16* __restrict__ gatesx) {
    __shared__ __align__(16) unsigned short Wl[G_][136];  // bf16 W_ih, padded
    __shared__ __align__(16) unsigned short Al[32][136];  // bf16 wx tile (overlaid: red)
    __shared__ float bias[G_];
    __shared__ float aw_s[T_];
    __shared__ float a_s[N_];
    __shared__ float wred[4];
    const int tid = threadIdx.x;
    const int b = blockIdx.x;

    for (int q = tid; q < G_ * 32; q += 256) {
        int r = q >> 5, c4 = (q & 31) << 2;
        float4 v = *(const float4*)(W_ih + r * N_ + c4);
        Wl[r][c4 + 0] = f2bf(v.x); Wl[r][c4 + 1] = f2bf(v.y);
        Wl[r][c4 + 2] = f2bf(v.z); Wl[r][c4 + 3] = f2bf(v.w);
    }
    bias[tid] = b_ih[tid] + b_hh[tid];
    aw_s[tid] = attn_w[2 * H_ + tid];
    __syncthreads();

    // ---- Phase A: attention softmax (shift-invariance kills h/c/bias) ----
    float (*red)[128] = (float(*)[128])&Al[0][0];
    const int n0 = (tid & 31) << 2;
    const int tg = tid >> 5;
    const float* xb = x + (size_t)b * (T_ * N_);
    {
        float p0 = 0.f, p1 = 0.f, p2 = 0.f, p3 = 0.f;
        for (int t = tg; t < T_; t += 8) {
            float4 v = *(const float4*)(xb + t * N_ + n0);
            float w = aw_s[t];
            p0 += v.x * w; p1 += v.y * w; p2 += v.z * w; p3 += v.w * w;
        }
        red[tg][n0 + 0] = p0; red[tg][n0 + 1] = p1;
        red[tg][n0 + 2] = p2; red[tg][n0 + 3] = p3;
    }
    __syncthreads();
    {
        float s = 0.f;
        if (tid < 128) {
            #pragma unroll
            for (int g = 0; g < 8; ++g) s += red[g][tid];
        }
        float m = (tid < 128) ? s : -1e30f;
        #pragma unroll
        for (int d = 1; d < 64; d <<= 1) m = fmaxf(m, __shfl_xor(m, d));
        if ((tid & 63) == 0) wred[tid >> 6] = m;
        __syncthreads();
        m = fmaxf(wred[0], wred[1]);
        __syncthreads();
        float e = (tid < 128) ? __expf(s - m) : 0.f;
        float z = e;
        #pragma unroll
        for (int d = 1; d < 64; d <<= 1) z += __shfl_xor(z, d);
        if ((tid & 63) == 0) wred[tid >> 6] = z;
        __syncthreads();
        z = wred[0] + wred[1];
        if (tid < 128) a_s[tid] = e / z;
    }
    __syncthreads();

    // ---- Phase B: weighting + MFMA GEMM ----
    const int lane = tid & 63;
    const int lr = lane & 15;
    const int lk = (lane >> 4) << 3;
    const int gc0 = (tid >> 6) << 6;
    const int orow = (lane >> 4) << 2;

    for (int st = 0; st < 8; ++st) {
        const int r0 = b * T_ + st * 32;
        __syncthreads();
        for (int q = tid; q < 32 * 32; q += 256) {
            int r = q >> 5, c4 = (q & 31) << 2;
            size_t off = (size_t)(r0 + r) * N_ + c4;
            float4 v = *(const float4*)(x + off);
            float4 w;
            w.x = a_s[c4 + 0] * v.x; w.y = a_s[c4 + 1] * v.y;
            w.z = a_s[c4 + 2] * v.z; w.w = a_s[c4 + 3] * v.w;
            *(float4*)(iw + off) = w;            // output 0 (f32, exact)
            Al[r][c4 + 0] = f2bf(w.x); Al[r][c4 + 1] = f2bf(w.y);
            Al[r][c4 + 2] = f2bf(w.z); Al[r][c4 + 3] = f2bf(w.w);
        }
        __syncthreads();

        f32x4 acc[2][4];
        #pragma unroll
        for (int mt = 0; mt < 2; ++mt)
            #pragma unroll
            for (int nt = 0; nt < 4; ++nt)
                acc[mt][nt] = (f32x4){0.f, 0.f, 0.f, 0.f};

        #pragma unroll
        for (int kk = 0; kk < N_; kk += 32) {
            short8 af0 = *(const short8*)(&Al[lr][kk + lk]);
            short8 af1 = *(const short8*)(&Al[16 + lr][kk + lk]);
            #pragma unroll
            for (int nt = 0; nt < 4; ++nt) {
                short8 bfv = *(const short8*)(&Wl[gc0 + nt * 16 + lr][kk + lk]);
                acc[0][nt] = __builtin_amdgcn_mfma_f32_16x16x32_bf16(af0, bfv, acc[0][nt], 0, 0, 0);
                acc[1][nt] = __builtin_amdgcn_mfma_f32_16x16x32_bf16(af1, bfv, acc[1][nt], 0, 0, 0);
            }
        }
        // D: col = gc0+nt*16+lr (gate index), row = mt*16+(lane>>4)*4+reg
        #pragma unroll
        for (int mt = 0; mt < 2; ++mt) {
            #pragma unroll
            for (int nt = 0; nt < 4; ++nt) {
                int col = gc0 + nt * 16 + lr;
                float bs = bias[col];
                int cell = col & 63, qg = col >> 6;
                #pragma unroll
                for (int rg = 0; rg < 4; ++rg) {
                    int rr = r0 + mt * 16 + orow + rg;
                    gatesx[((size_t)rr * H_ + cell) * 4 + qg] =
                        (_Float16)(acc[mt][nt][rg] + bs);
                }
            }
        }
    }
}

// ---------------------------------------------------------------------------
// K3: LSTM recurrence, single-wave blocks (64 thr), 512 blocks.
// Round-13 insight: vmcnt retires IN FIFO ORDER, so the per-step enc STORE
// sits ahead of the next gate LOAD in the counter -- waiting for the load
// also waits for the ~1000cy HBM store ack, with only ~1 step of slack.
// Every variant since round 2 had this pattern; it's the invariant ~500+
// cy/step stall. Fix: batch enc stores per 4-step group (h in named regs,
// 4 stores at group end) -> store acks get ~8 steps of slack and loads
// consumed in group i+1 precede group-i stores in the FIFO entirely.
// Loads: depth-4 prefetch via named gA..gD, no rotation moves.
// ---------------------------------------------------------------------------
__global__ __attribute__((amdgpu_flat_work_group_size(64, 64)))
__attribute__((amdgpu_waves_per_eu(1, 1)))
void k_rnn12(const _Float16* __restrict__ gatesx,
             const uint4* __restrict__ wpack,
             float* __restrict__ enc) {
    __shared__ __align__(16) _Float16 hs[H_];   // h_t (f16), 128 B
    const int j = threadIdx.x;   // cell index
    const int b = blockIdx.x;

    // 32 x dwordx4 = 128 VGPRs of packed half2 weights (4 gate rows x 8 quads)
    uint4 wv[4][8];
    #pragma unroll
    for (int g = 0; g < 4; ++g) {
        #pragma unroll
        for (int q = 0; q < 8; ++q) {
            unsigned voff = (unsigned)((((g << 3) + q) * 64 + j) << 4);
            asm volatile("global_load_dwordx4 %0, %1, %2"
                         : "=v"(wv[g][q]) : "v"(voff), "s"(wpack) : "memory");
        }
    }
    asm volatile("s_waitcnt vmcnt(0)" ::: "memory");

    hs[j] = (_Float16)0.f;     // h_{-1} = 0 (single wave: DS in-order)
    float c = 0.f;
    const unsigned hbase = (unsigned)(uintptr_t)&hs[0];   // LDS byte offset

    const _Float16* gx = gatesx + ((size_t)b * T_ * H_ + j) * 4;
    float* ep = enc + (size_t)b * T_ * H_ + j;

    uint2 gA = *(const uint2*)(gx);                  // t = 0
    uint2 gB = *(const uint2*)(gx + G_);             // t = 1
    uint2 gC = *(const uint2*)(gx + 2 * (size_t)G_); // t = 2
    uint2 gD = *(const uint2*)(gx + 3 * (size_t)G_); // t = 3

#define DOTQ(Q, CH)                                                         \
        do {                                                                \
            a0 = __builtin_amdgcn_fdot2(u2h2(wv[0][Q].x), u2h2(CH.x), a0, false); \
            a1 = __builtin_amdgcn_fdot2(u2h2(wv[1][Q].x), u2h2(CH.x), a1, false); \
            a2 = __builtin_amdgcn_fdot2(u2h2(wv[2][Q].x), u2h2(CH.x), a2, false); \
            a3 = __builtin_amdgcn_fdot2(u2h2(wv[3][Q].x), u2h2(CH.x), a3, false); \
            a0 = __builtin_amdgcn_fdot2(u2h2(wv[0][Q].y), u2h2(CH.y), a0, false); \
            a1 = __builtin_amdgcn_fdot2(u2h2(wv[1][Q].y), u2h2(CH.y), a1, false); \
            a2 = __builtin_amdgcn_fdot2(u2h2(wv[2][Q].y), u2h2(CH.y), a2, false); \
            a3 = __builtin_amdgcn_fdot2(u2h2(wv[3][Q].y), u2h2(CH.y), a3, false); \
            a0 = __builtin_amdgcn_fdot2(u2h2(wv[0][Q].z), u2h2(CH.z), a0, false); \
            a1 = __builtin_amdgcn_fdot2(u2h2(wv[1][Q].z), u2h2(CH.z), a1, false); \
            a2 = __builtin_amdgcn_fdot2(u2h2(wv[2][Q].z), u2h2(CH.z), a2, false); \
            a3 = __builtin_amdgcn_fdot2(u2h2(wv[3][Q].z), u2h2(CH.z), a3, false); \
            a0 = __builtin_amdgcn_fdot2(u2h2(wv[0][Q].w), u2h2(CH.w), a0, false); \
            a1 = __builtin_amdgcn_fdot2(u2h2(wv[1][Q].w), u2h2(CH.w), a1, false); \
            a2 = __builtin_amdgcn_fdot2(u2h2(wv[2][Q].w), u2h2(CH.w), a2, false); \
            a3 = __builtin_amdgcn_fdot2(u2h2(wv[3][Q].w), u2h2(CH.w), a3, false); \
        } while (0)

    // One step: consume GREG, reload it for step TNEXT, update h in HOUT
    // (register) and hs (LDS, for next step's broadcast). NO global store.
#define STEP(GREG, TNEXT, HOUT)                                             \
    {                                                                       \
        half2_t gif = u2h2(GREG.x), ggo = u2h2(GREG.y);                     \
        float a0 = (float)gif.x, a1 = (float)gif.y;                         \
        float a2 = (float)ggo.x, a3 = (float)ggo.y;                         \
        int tn_ = (TNEXT) < T_ ? (TNEXT) : (T_ - 1);                        \
        GREG = *(const uint2*)(gx + (size_t)tn_ * G_);                      \
        uint4 c0, c1, c2, c3, c4, c5, c6, c7;                               \
        asm volatile(                                                       \
            "ds_read_b128 %0, %8 offset:0\n\t"                              \
            "ds_read_b128 %1, %8 offset:16\n\t"                             \
            "ds_read_b128 %2, %8 offset:32\n\t"                             \
            "ds_read_b128 %3, %8 offset:48\n\t"                             \
            "ds_read_b128 %4, %8 offset:64\n\t"                             \
            "ds_read_b128 %5, %8 offset:80\n\t"                             \
            "ds_read_b128 %6, %8 offset:96\n\t"                             \
            "ds_read_b128 %7, %8 offset:112"                                \
            : "=&v"(c0), "=&v"(c1), "=&v"(c2), "=&v"(c3),                   \
              "=&v"(c4), "=&v"(c5), "=&v"(c6), "=&v"(c7)                    \
            : "v"(hbase)                                                    \
            : "memory");                                                    \
        asm volatile("s_waitcnt lgkmcnt(0)" ::: "memory");                  \
        __builtin_amdgcn_sched_barrier(0);                                  \
        DOTQ(0, c0); DOTQ(1, c1); DOTQ(2, c2); DOTQ(3, c3);                 \
        DOTQ(4, c4); DOTQ(5, c5); DOTQ(6, c6); DOTQ(7, c7);                 \
        float si = 1.f / (1.f + __expf(-a0));                               \
        float sf = 1.f / (1.f + __expf(-a1));                               \
        float tg = 1.f - 2.f / (__expf(2.f * a2) + 1.f);                    \
        float so = 1.f / (1.f + __expf(-a3));                               \
        c = sf * c + si * tg;                                               \
        float tc = 1.f - 2.f / (__expf(2.f * c) + 1.f);                     \
        HOUT = so * tc;                                                     \
        hs[j] = (_Float16)HOUT;   /* in-order DS: visible next step */      \
    }

    for (int t = 0; t < T_; t += 4) {
        float h0, h1, h2, h3;
        STEP(gA, t + 4, h0);
        STEP(gB, t + 5, h1);
        STEP(gC, t + 6, h2);
        STEP(gD, t + 7, h3);
        // group-end store burst: acks have ~2 groups (~8 steps) of slack
        // before any gate-load use sits behind them in the vmcnt FIFO.
        *(ep + (size_t)(t + 0) * H_) = h0;
        *(ep + (size_t)(t + 1) * H_) = h1;
        *(ep + (size_t)(t + 2) * H_) = h2;
        *(ep + (size_t)(t + 3) * H_) = h3;
    }
#undef STEP
#undef DOTQ
}

extern "C" void kernel_launch(void* const* d_in, const int* in_sizes, int n_in,
                              void* d_out, int out_size, void* d_ws, size_t ws_size,
                              hipStream_t stream) {
    if (n_in < 7 || in_sizes[0] != B_ * T_ * N_) return;

    const float* x    = (const float*)d_in[0];
    const float* aw   = (const float*)d_in[1];
    // d_in[2] (attn_b) provably cancels in the softmax — unused.
    const float* W_ih = (const float*)d_in[3];
    const float* W_hh = (const float*)d_in[4];
    const float* b_ih = (const float*)d_in[5];
    const float* b_hh = (const float*)d_in[6];

    float* iwp = (float*)d_out;                          // (B,T,N) f32
    float* enc = (float*)d_out + (size_t)B_ * T_ * N_;   // (B,T,H) f32

    size_t gx_bytes = (size_t)B_ * T_ * G_ * sizeof(_Float16);   // 33.5 MB
    _Float16* gatesx = (_Float16*)d_ws;
    uint4* wpack = (uint4*)((char*)d_ws + gx_bytes);             // 32 KB
    size_t need = gx_bytes + 2048 * sizeof(uint4);
    if (ws_size < need) return;  // fail loudly rather than corrupt

    hipLaunchKernelGGL(k_wpack, dim3(8), dim3(256), 0, stream, W_hh, wpack);
    hipLaunchKernelGGL(k_awgemm, dim3(B_), dim3(256), 0, stream,
                       x, aw, W_ih, b_ih, b_hh, iwp, gatesx);
    hipLaunchKernelGGL(k_rnn12, dim3(B_), dim3(64), 0, stream, gatesx, wpack, enc);
}